// Round 14
// baseline (127.522 us; speedup 1.0000x reference)
//
#include <hip/hip_runtime.h>
#include <math.h>

#define NROW 4096
#define FDIM 512
#define MARGIN 1.0f
#define NLAB 16
#define PREP_BLK 1024   // blocks 0..1023 convert rows; block 1024 sorts

typedef __attribute__((ext_vector_type(8))) short short8;
typedef __attribute__((ext_vector_type(4))) float floatx4;

__device__ inline unsigned short f2bf(float x) {
    unsigned u = __float_as_uint(x);
    return (unsigned short)((u + 0x7FFFu + ((u >> 16) & 1u)) >> 16);
}
__device__ inline void glds16(const unsigned short* g, unsigned short* l) {
    __builtin_amdgcn_global_load_lds(
        (const __attribute__((address_space(1))) unsigned int*)g,
        (__attribute__((address_space(3))) unsigned int*)l, 16, 0, 0);
}
// counted-wait + barrier + schedule pin (rule #18 / m201 pattern)
#define WAIT_VM_BARRIER(N)                                          \
    do {                                                            \
        asm volatile("s_waitcnt vmcnt(" #N ")" ::: "memory");       \
        __builtin_amdgcn_s_barrier();                               \
        __builtin_amdgcn_sched_barrier(0);                          \
    } while (0)

// fast |v|: D = dsq * rsqrt(dsq)  (clamped so masked diagonal stays finite)
__device__ inline float fast_sqrt_pos(float dsq) {
    float c = fmaxf(dsq, 1e-20f);
    return c * __frsqrt_rn(c);
}

// ---------------------------------------------------------------------------
// Prep: bf16 convert + row norms + zero rns/loss. 1024 blocks x 256 threads,
// 4 rows/block (one wave per row), unit-stride loads/stores (r13-verified).
// Block 1024: counting sort + worklist + num_pos.
// ---------------------------------------------------------------------------
__global__ __launch_bounds__(256) void prep_kernel(
    const float* __restrict__ a, const float* __restrict__ b,
    const int* __restrict__ labels,
    unsigned short* __restrict__ abf, unsigned short* __restrict__ bbf,
    float* __restrict__ na, float* __restrict__ nb,
    float* __restrict__ rns, float* __restrict__ loss,
    int* __restrict__ perm, int* __restrict__ goff,
    int* __restrict__ wl, int* __restrict__ wlmeta) {
    const int t = threadIdx.x;

    if (blockIdx.x == PREP_BLK) {
        __shared__ int hist[NLAB], off[NLAB], cur[NLAB];
        if (t < NLAB) hist[t] = 0;
        __syncthreads();
        for (int i = t; i < NROW; i += 256) atomicAdd(&hist[labels[i] & 15], 1);
        __syncthreads();
        if (t == 0) {
            int acc = 0;
            for (int g = 0; g < NLAB; ++g) { off[g] = acc; acc += hist[g]; }
            int n = 0;
            long long np = 0;
            for (int g = 0; g < NLAB; ++g) {
                goff[g] = off[g];
                int c = hist[g];
                np += (long long)c * (long long)(c - 1);
                int nt = (c + 63) >> 6;
                for (int ti = 0; ti < nt; ++ti)
                    for (int tj = 0; tj < nt; ++tj)
                        wl[n++] = (g << 12) | (ti << 6) | tj;
            }
            goff[NLAB] = NROW;
            wlmeta[0] = n;          // worklist length
            wlmeta[1] = (int)np;    // num_pos
            wlmeta[2] = 0;          // done-counter for fused finalize
            loss[0]   = 0.f;
        }
        __syncthreads();
        if (t < NLAB) cur[t] = off[t];
        __syncthreads();
        for (int i = t; i < NROW; i += 256) {
            int pos = atomicAdd(&cur[labels[i] & 15], 1);
            perm[pos] = i;
        }
        return;
    }

    const int grp = t >> 6;                 // 0..3: row within block (wave)
    const int ln  = t & 63;                 // lane
    const int row = blockIdx.x * 4 + grp;
    const float4* a4 = (const float4*)(a + (size_t)row * FDIM);
    const float4* b4 = (const float4*)(b + (size_t)row * FDIM);
    float4 va0 = a4[ln], va1 = a4[ln + 64];     // unit-stride per instruction
    float4 vb0 = b4[ln], vb1 = b4[ln + 64];
    float sa = va0.x * va0.x + va0.y * va0.y + va0.z * va0.z + va0.w * va0.w
             + va1.x * va1.x + va1.y * va1.y + va1.z * va1.z + va1.w * va1.w;
    float sb = vb0.x * vb0.x + vb0.y * vb0.y + vb0.z * vb0.z + vb0.w * vb0.w
             + vb1.x * vb1.x + vb1.y * vb1.y + vb1.z * vb1.z + vb1.w * vb1.w;
    ushort4 ua0 = { f2bf(va0.x), f2bf(va0.y), f2bf(va0.z), f2bf(va0.w) };
    ushort4 ua1 = { f2bf(va1.x), f2bf(va1.y), f2bf(va1.z), f2bf(va1.w) };
    ushort4 ub0 = { f2bf(vb0.x), f2bf(vb0.y), f2bf(vb0.z), f2bf(vb0.w) };
    ushort4 ub1 = { f2bf(vb1.x), f2bf(vb1.y), f2bf(vb1.z), f2bf(vb1.w) };
    ushort4* au = (ushort4*)(abf + (size_t)row * FDIM);
    ushort4* bu = (ushort4*)(bbf + (size_t)row * FDIM);
    au[ln]      = ua0;
    au[ln + 64] = ua1;
    bu[ln]      = ub0;
    bu[ln + 64] = ub1;
    #pragma unroll
    for (int o = 32; o > 0; o >>= 1) {
        sa += __shfl_down(sa, o);
        sb += __shfl_down(sb, o);
    }
    if (ln == 0) {
        na[row] = sa;
        nb[row] = sb;
        rns[row] = 0.f;
    }
}

// ---------------------------------------------------------------------------
// Negsum pass (r9/r13 body verbatim — confirmed best): 256x256 tile, 256
// blocks (1/CU), 1024 threads (16 waves 4x4 -> 4 waves/SIMD). BK=32,
// quad-buffered 128KB LDS, prefetch depth 3, counted vmcnt(4) (T4).
// Chunk-XOR swizzle both sides (rule #21). Branchless rsqrt epilogue;
// wj-merged rns atomics.
// ---------------------------------------------------------------------------
__global__ __launch_bounds__(1024, 4) void pass_neg(
    const unsigned short* __restrict__ abf, const unsigned short* __restrict__ bbf,
    const int* __restrict__ labels,
    const float* __restrict__ na, const float* __restrict__ nb,
    float* __restrict__ rns)
{
    // 4 buffers x (As 16KB + Bs 16KB) = 128KB
    __shared__ __align__(16) unsigned short arena[65536];
    __shared__ float rpart[4][256];                        // per-wj row partials

    const int t    = threadIdx.x;
    const int lane = t & 63;
    const int w    = t >> 6;          // 0..15
    const int wi   = w >> 2;          // 0..3  (i-quarter, 64 rows)
    const int wj   = w & 3;           // 0..3  (j-quarter, 64 cols)
    const int lr   = lane & 15;
    const int lq   = lane >> 4;

    // XCD-aware bijective swizzle (256 blocks, 8 XCDs)
    const int bid = blockIdx.x;
    const int wg  = (bid & 7) * 32 + (bid >> 3);
    const int by  = wg >> 4, bx = wg & 15;
    const int ti  = by * 256;         // b-row (i) origin
    const int tj  = bx * 256;         // a-row (j) origin

    floatx4 acc[4][4];
    #pragma unroll
    for (int i = 0; i < 4; ++i)
        #pragma unroll
        for (int j = 0; j < 4; ++j)
            acc[i][j] = (floatx4){0.f, 0.f, 0.f, 0.f};

    // stage: 2 glds16/thread. chunk t: row = t>>2 (0..255), q = t&3,
    // source chunk pre-swizzled qs = q ^ ((row>>1)&3); LDS dest linear.
    const int srow = t >> 2;
    const int sqs  = (t & 3) ^ ((srow >> 1) & 3);
    const unsigned offA = (unsigned)(tj + srow) * FDIM + sqs * 8;
    const unsigned offB = (unsigned)(ti + srow) * FDIM + sqs * 8;

    auto stage = [&](int s) {
        unsigned short* As = arena + (s & 3) * 16384;
        unsigned short* Bs = As + 8192;
        const int kk = s * 32;
        glds16(abf + offA + kk, As + t * 8);
        glds16(bbf + offB + kk, Bs + t * 8);
    };

    stage(0);
    stage(1);
    stage(2);
    WAIT_VM_BARRIER(4);   // stage0 complete; stages 1,2 (4 loads) in flight

    #pragma unroll
    for (int it = 0; it < 16; ++it) {
        if (it < 13) stage(it + 3);

        const unsigned short* As = arena + (it & 3) * 16384;
        const unsigned short* Bs = As + 8192;
        short8 af[4], bv[4];
        #pragma unroll
        for (int ri = 0; ri < 4; ++ri) {
            int R = wi * 64 + ri * 16 + lr;
            af[ri] = *(const short8*)
                &Bs[R * 32 + ((lq ^ ((R >> 1) & 3))) * 8];
        }
        #pragma unroll
        for (int rj = 0; rj < 4; ++rj) {
            int R = wj * 64 + rj * 16 + lr;
            bv[rj] = *(const short8*)
                &As[R * 32 + ((lq ^ ((R >> 1) & 3))) * 8];
        }
        __builtin_amdgcn_s_setprio(1);
        #pragma unroll
        for (int ri = 0; ri < 4; ++ri)
            #pragma unroll
            for (int rj = 0; rj < 4; ++rj)
                acc[ri][rj] = __builtin_amdgcn_mfma_f32_16x16x32_bf16(
                    af[ri], bv[rj], acc[ri][rj], 0, 0, 0);
        __builtin_amdgcn_s_setprio(0);

        if (it < 13) {
            WAIT_VM_BARRIER(4);   // stage(it+1) done; it+2,it+3 in flight
        } else if (it == 13) {
            WAIT_VM_BARRIER(2);   // stage14 done; stage15 in flight
        } else if (it == 14) {
            WAIT_VM_BARRIER(0);
        }
    }

    // branchless epilogue: C/D layout col = lane&15, row = quad*4 + reg
    int   ljv[4]; float najv[4];
    #pragma unroll
    for (int rj = 0; rj < 4; ++rj) {
        int jl = wj * 64 + rj * 16 + lr;
        ljv[rj]  = labels[tj + jl];
        najv[rj] = na[tj + jl];
    }
    #pragma unroll
    for (int ri = 0; ri < 4; ++ri) {
        float rs[4] = {0.f, 0.f, 0.f, 0.f};
        int liv[4]; float nbv[4];
        #pragma unroll
        for (int r = 0; r < 4; ++r) {
            int il = wi * 64 + ri * 16 + lq * 4 + r;
            liv[r] = labels[ti + il];
            nbv[r] = nb[ti + il];
        }
        #pragma unroll
        for (int rj = 0; rj < 4; ++rj)
            #pragma unroll
            for (int r = 0; r < 4; ++r) {
                float dsq  = nbv[r] + najv[rj] - 2.f * acc[ri][rj][r];
                float D    = fast_sqrt_pos(dsq);
                float mask = (liv[r] != ljv[rj]) ? 1.f : 0.f;
                rs[r] = fmaf(mask, __expf(MARGIN - D), rs[r]);
            }
        #pragma unroll
        for (int r = 0; r < 4; ++r) {
            #pragma unroll
            for (int o = 8; o > 0; o >>= 1) rs[r] += __shfl_down(rs[r], o, 16);
        }
        if (lr == 0) {
            #pragma unroll
            for (int r = 0; r < 4; ++r)
                rpart[wj][wi * 64 + ri * 16 + lq * 4 + r] = rs[r];
        }
    }
    __syncthreads();
    if (t < 256) {
        float s = rpart[0][t] + rpart[1][t] + rpart[2][t] + rpart[3][t];
        atomicAdd(&rns[ti + t], s);
    }
}

// ---------------------------------------------------------------------------
// Phase-2 (r9 body; grid widened 256->512 so every block handles <=1 of the
// ~350 worklist items — halves the pos critical path; 64KB LDS -> 2
// blocks/CU co-resident). Same-label 64x64 tiles, gathered-row GEMM, 512
// threads (8 waves 2x4), SINGLE-SLAB whole 64x512 A/B tiles, ONE vmcnt(0)
// drain, 16 K-slices barrier-free. Last block writes final output.
// ---------------------------------------------------------------------------
__global__ __launch_bounds__(512) void pass2_pos(
    const unsigned short* __restrict__ abf, const unsigned short* __restrict__ bbf,
    const float* __restrict__ na, const float* __restrict__ nb,
    const float* __restrict__ rns,
    const int* __restrict__ perm, const int* __restrict__ goff,
    const int* __restrict__ wl, const int* __restrict__ wlmeta,
    float* __restrict__ loss_sum, int* __restrict__ done,
    float* __restrict__ out)
{
    __shared__ __align__(16) unsigned short arena[65536];  // As 64KB | Bs 64KB
    __shared__ int   rows_i[64], rows_j[64];
    __shared__ float rbi_s[64], rbj_s[64], nbi_s[64], naj_s[64];
    __shared__ float part[8];

    const int t    = threadIdx.x;
    const int lane = t & 63;
    const int w    = t >> 6;          // 0..7
    const int wi   = w >> 2;          // 0..1  (i-half, 32 rows)
    const int wj   = w & 3;           // 0..3  (j-quarter, 16 cols)
    const int lr   = lane & 15;
    const int lq   = lane >> 4;
    const int nwl  = wlmeta[0];

    float local = 0.f;

    for (int item = blockIdx.x; item < nwl; item += gridDim.x) {
        __syncthreads();   // previous item's readers done with meta/arena
        int e  = wl[item];
        int g  = e >> 12, ti = (e >> 6) & 63, tj = e & 63;
        int gb = goff[g], ge = goff[g + 1];
        int cnt = ge - gb;

        if (t < 64) {
            int idx = gb + ti * 64 + t;
            int ig  = perm[idx < ge ? idx : gb];   // pad with first row of group
            rows_i[t] = ig;
            rbi_s[t]  = rns[ig];
            nbi_s[t]  = nb[ig];
        } else if (t < 128) {
            int u   = t - 64;
            int idx = gb + tj * 64 + u;
            int jg  = perm[idx < ge ? idx : gb];
            rows_j[u] = jg;
            rbj_s[u]  = rns[jg];
            naj_s[u]  = na[jg];
        }
        __syncthreads();

        // stage entire 64x512 tiles: per side 4096 chunks (row=c>>6, q=c&63),
        // 8 c-rounds x 2 sides = 16 glds16/thread; source pre-swizzled
        // q^(row&7) (stays within 128B group so coalescing unchanged).
        #pragma unroll
        for (int l = 0; l < 8; ++l) {
            int c   = t + l * 512;           // 0..4095
            int row = c >> 6;
            int qs  = (c & 63) ^ (row & 7);
            glds16(abf + (size_t)rows_j[row] * FDIM + qs * 8, arena + c * 8);
            glds16(bbf + (size_t)rows_i[row] * FDIM + qs * 8,
                   arena + 32768 + c * 8);
        }
        WAIT_VM_BARRIER(0);

        floatx4 acc[2];
        acc[0] = (floatx4){0.f, 0.f, 0.f, 0.f};
        acc[1] = (floatx4){0.f, 0.f, 0.f, 0.f};

        const unsigned short* As = arena;           // a-side (cols j)
        const unsigned short* Bs = arena + 32768;   // b-side (rows i)
        #pragma unroll
        for (int ks = 0; ks < 16; ++ks) {
            short8 af[2], bv;
            #pragma unroll
            for (int ri = 0; ri < 2; ++ri) {
                int R  = wi * 32 + ri * 16 + lr;
                int cs = (ks * 4 + lq) ^ (R & 7);
                af[ri] = *(const short8*)&Bs[R * 512 + cs * 8];
            }
            {
                int R  = wj * 16 + lr;
                int cs = (ks * 4 + lq) ^ (R & 7);
                bv = *(const short8*)&As[R * 512 + cs * 8];
            }
            #pragma unroll
            for (int ri = 0; ri < 2; ++ri)
                acc[ri] = __builtin_amdgcn_mfma_f32_16x16x32_bf16(
                    af[ri], bv, acc[ri], 0, 0, 0);
        }

        // epilogue: J = log(rns_i + rns_j) + D, hinged, squared
        int  jl  = wj * 16 + lr;
        bool vj  = (tj * 64 + jl) < cnt;
        int  jg  = rows_j[jl];
        float nav = naj_s[jl], rbj = rbj_s[jl];
        #pragma unroll
        for (int ri = 0; ri < 2; ++ri) {
            #pragma unroll
            for (int r = 0; r < 4; ++r) {
                int  il = wi * 32 + ri * 16 + lq * 4 + r;
                bool vi = (ti * 64 + il) < cnt;
                if (vi && vj && rows_i[il] != jg) {
                    float dsq = nbi_s[il] + nav - 2.f * acc[ri][r];
                    float D   = fast_sqrt_pos(dsq);
                    float J   = __logf(rbi_s[il] + rbj) + D;
                    float h   = fmaxf(J, 0.f);
                    local += h * h;
                }
            }
        }
    }

    #pragma unroll
    for (int o = 32; o > 0; o >>= 1) local += __shfl_down(local, o);
    if (lane == 0) part[w] = local;
    __syncthreads();
    if (t == 0) {
        float s = 0.f;
        #pragma unroll
        for (int i = 0; i < 8; ++i) s += part[i];
        atomicAdd(loss_sum, s);
        __threadfence();
        int old = atomicAdd(done, 1);
        if (old == (int)gridDim.x - 1) {
            __threadfence();
            float total = *(volatile float*)loss_sum;
            out[0] = total / (2.0f * (float)wlmeta[1]);
        }
    }
}

// ---------------------------------------------------------------------------
extern "C" void kernel_launch(void* const* d_in, const int* in_sizes, int n_in,
                              void* d_out, int out_size, void* d_ws, size_t ws_size,
                              hipStream_t stream) {
    const float* a      = (const float*)d_in[0];
    const float* b      = (const float*)d_in[1];
    const int*   labels = (const int*)d_in[2];
    float* out = (float*)d_out;

    // ws: abf(4MB) | bbf(4MB) | na,nb,rns,loss | perm,goff,wlmeta,wl  (~8.5MB)
    unsigned short* abf = (unsigned short*)d_ws;
    unsigned short* bbf = abf + (size_t)NROW * FDIM;
    float* fws  = (float*)(bbf + (size_t)NROW * FDIM);
    float* na   = fws;
    float* nb   = fws + NROW;
    float* rns  = fws + 2 * NROW;
    float* loss = fws + 3 * NROW;
    int* iws    = (int*)(fws + 3 * NROW + 4);
    int* perm   = iws;                 // NROW
    int* goff   = iws + NROW;          // 17
    int* wlmeta = iws + NROW + 20;     // [0]=n, [1]=num_pos, [2]=done
    int* wl     = iws + NROW + 24;     // <= 8192 worst case

    prep_kernel<<<PREP_BLK + 1, 256, 0, stream>>>(a, b, labels, abf, bbf,
                                                  na, nb, rns, loss,
                                                  perm, goff, wl, wlmeta);
    pass_neg<<<(NROW / 256) * (NROW / 256), 1024, 0, stream>>>(abf, bbf, labels,
                                                               na, nb, rns);
    pass2_pos<<<512, 512, 0, stream>>>(abf, bbf, na, nb, rns, perm, goff, wl,
                                       wlmeta, loss, &wlmeta[2], out);
}

// Round 15
// 122.262 us; speedup vs baseline: 1.0430x; 1.0430x over previous
//
#include <hip/hip_runtime.h>
#include <math.h>

#define NROW 4096
#define FDIM 512
#define MARGIN 1.0f
#define NLAB 16
#define PREP_BLK 1024   // blocks 0..1023 convert rows; block 1024 sorts

typedef __attribute__((ext_vector_type(8))) short short8;
typedef __attribute__((ext_vector_type(4))) float floatx4;

__device__ inline unsigned short f2bf(float x) {
    unsigned u = __float_as_uint(x);
    return (unsigned short)((u + 0x7FFFu + ((u >> 16) & 1u)) >> 16);
}
__device__ inline void glds16(const unsigned short* g, unsigned short* l) {
    __builtin_amdgcn_global_load_lds(
        (const __attribute__((address_space(1))) unsigned int*)g,
        (__attribute__((address_space(3))) unsigned int*)l, 16, 0, 0);
}
// counted-wait + barrier + schedule pin (rule #18 / m201 pattern)
#define WAIT_VM_BARRIER(N)                                          \
    do {                                                            \
        asm volatile("s_waitcnt vmcnt(" #N ")" ::: "memory");       \
        __builtin_amdgcn_s_barrier();                               \
        __builtin_amdgcn_sched_barrier(0);                          \
    } while (0)

// fast |v|: D = dsq * rsqrt(dsq)  (clamped so masked diagonal stays finite)
__device__ inline float fast_sqrt_pos(float dsq) {
    float c = fmaxf(dsq, 1e-20f);
    return c * __frsqrt_rn(c);
}

// ---------------------------------------------------------------------------
// Prep: bf16 convert + row norms + zero rns/loss. 1024 blocks x 256 threads,
// 4 rows/block (one wave per row), unit-stride loads/stores.
// Block 1024: counting sort + worklist + num_pos.
// ---------------------------------------------------------------------------
__global__ __launch_bounds__(256) void prep_kernel(
    const float* __restrict__ a, const float* __restrict__ b,
    const int* __restrict__ labels,
    unsigned short* __restrict__ abf, unsigned short* __restrict__ bbf,
    float* __restrict__ na, float* __restrict__ nb,
    float* __restrict__ rns, float* __restrict__ loss,
    int* __restrict__ perm, int* __restrict__ goff,
    int* __restrict__ wl, int* __restrict__ wlmeta) {
    const int t = threadIdx.x;

    if (blockIdx.x == PREP_BLK) {
        __shared__ int hist[NLAB], off[NLAB], cur[NLAB];
        if (t < NLAB) hist[t] = 0;
        __syncthreads();
        for (int i = t; i < NROW; i += 256) atomicAdd(&hist[labels[i] & 15], 1);
        __syncthreads();
        if (t == 0) {
            int acc = 0;
            for (int g = 0; g < NLAB; ++g) { off[g] = acc; acc += hist[g]; }
            int n = 0;
            long long np = 0;
            for (int g = 0; g < NLAB; ++g) {
                goff[g] = off[g];
                int c = hist[g];
                np += (long long)c * (long long)(c - 1);
                int nt = (c + 63) >> 6;
                for (int ti = 0; ti < nt; ++ti)
                    for (int tj = 0; tj < nt; ++tj)
                        wl[n++] = (g << 12) | (ti << 6) | tj;
            }
            goff[NLAB] = NROW;
            wlmeta[0] = n;          // worklist length
            wlmeta[1] = (int)np;    // num_pos
            wlmeta[2] = 0;          // done-counter for fused finalize
            loss[0]   = 0.f;
        }
        __syncthreads();
        if (t < NLAB) cur[t] = off[t];
        __syncthreads();
        for (int i = t; i < NROW; i += 256) {
            int pos = atomicAdd(&cur[labels[i] & 15], 1);
            perm[pos] = i;
        }
        return;
    }

    const int grp = t >> 6;                 // 0..3: row within block (wave)
    const int ln  = t & 63;                 // lane
    const int row = blockIdx.x * 4 + grp;
    const float4* a4 = (const float4*)(a + (size_t)row * FDIM);
    const float4* b4 = (const float4*)(b + (size_t)row * FDIM);
    float4 va0 = a4[ln], va1 = a4[ln + 64];     // unit-stride per instruction
    float4 vb0 = b4[ln], vb1 = b4[ln + 64];
    float sa = va0.x * va0.x + va0.y * va0.y + va0.z * va0.z + va0.w * va0.w
             + va1.x * va1.x + va1.y * va1.y + va1.z * va1.z + va1.w * va1.w;
    float sb = vb0.x * vb0.x + vb0.y * vb0.y + vb0.z * vb0.z + vb0.w * vb0.w
             + vb1.x * vb1.x + vb1.y * vb1.y + vb1.z * vb1.z + vb1.w * vb1.w;
    ushort4 ua0 = { f2bf(va0.x), f2bf(va0.y), f2bf(va0.z), f2bf(va0.w) };
    ushort4 ua1 = { f2bf(va1.x), f2bf(va1.y), f2bf(va1.z), f2bf(va1.w) };
    ushort4 ub0 = { f2bf(vb0.x), f2bf(vb0.y), f2bf(vb0.z), f2bf(vb0.w) };
    ushort4 ub1 = { f2bf(vb1.x), f2bf(vb1.y), f2bf(vb1.z), f2bf(vb1.w) };
    ushort4* au = (ushort4*)(abf + (size_t)row * FDIM);
    ushort4* bu = (ushort4*)(bbf + (size_t)row * FDIM);
    au[ln]      = ua0;
    au[ln + 64] = ua1;
    bu[ln]      = ub0;
    bu[ln + 64] = ub1;
    #pragma unroll
    for (int o = 32; o > 0; o >>= 1) {
        sa += __shfl_down(sa, o);
        sb += __shfl_down(sb, o);
    }
    if (ln == 0) {
        na[row] = sa;
        nb[row] = sb;
        rns[row] = 0.f;
    }
}

// ---------------------------------------------------------------------------
// Negsum pass (champion body, measured best @123.0us): 256x256 tile, 256
// blocks (1/CU), 1024 threads (16 waves 4x4 -> 4 waves/SIMD). BK=32,
// quad-buffered 128KB LDS, prefetch depth 3, counted vmcnt(4) (T4).
// Chunk-XOR swizzle both sides (rule #21). Branchless rsqrt epilogue;
// wj-merged rns atomics.
// ---------------------------------------------------------------------------
__global__ __launch_bounds__(1024, 4) void pass_neg(
    const unsigned short* __restrict__ abf, const unsigned short* __restrict__ bbf,
    const int* __restrict__ labels,
    const float* __restrict__ na, const float* __restrict__ nb,
    float* __restrict__ rns)
{
    // 4 buffers x (As 16KB + Bs 16KB) = 128KB
    __shared__ __align__(16) unsigned short arena[65536];
    __shared__ float rpart[4][256];                        // per-wj row partials

    const int t    = threadIdx.x;
    const int lane = t & 63;
    const int w    = t >> 6;          // 0..15
    const int wi   = w >> 2;          // 0..3  (i-quarter, 64 rows)
    const int wj   = w & 3;           // 0..3  (j-quarter, 64 cols)
    const int lr   = lane & 15;
    const int lq   = lane >> 4;

    // XCD-aware bijective swizzle (256 blocks, 8 XCDs)
    const int bid = blockIdx.x;
    const int wg  = (bid & 7) * 32 + (bid >> 3);
    const int by  = wg >> 4, bx = wg & 15;
    const int ti  = by * 256;         // b-row (i) origin
    const int tj  = bx * 256;         // a-row (j) origin

    floatx4 acc[4][4];
    #pragma unroll
    for (int i = 0; i < 4; ++i)
        #pragma unroll
        for (int j = 0; j < 4; ++j)
            acc[i][j] = (floatx4){0.f, 0.f, 0.f, 0.f};

    // stage: 2 glds16/thread. chunk t: row = t>>2 (0..255), q = t&3,
    // source chunk pre-swizzled qs = q ^ ((row>>1)&3); LDS dest linear.
    const int srow = t >> 2;
    const int sqs  = (t & 3) ^ ((srow >> 1) & 3);
    const unsigned offA = (unsigned)(tj + srow) * FDIM + sqs * 8;
    const unsigned offB = (unsigned)(ti + srow) * FDIM + sqs * 8;

    auto stage = [&](int s) {
        unsigned short* As = arena + (s & 3) * 16384;
        unsigned short* Bs = As + 8192;
        const int kk = s * 32;
        glds16(abf + offA + kk, As + t * 8);
        glds16(bbf + offB + kk, Bs + t * 8);
    };

    stage(0);
    stage(1);
    stage(2);
    WAIT_VM_BARRIER(4);   // stage0 complete; stages 1,2 (4 loads) in flight

    #pragma unroll
    for (int it = 0; it < 16; ++it) {
        if (it < 13) stage(it + 3);

        const unsigned short* As = arena + (it & 3) * 16384;
        const unsigned short* Bs = As + 8192;
        short8 af[4], bv[4];
        #pragma unroll
        for (int ri = 0; ri < 4; ++ri) {
            int R = wi * 64 + ri * 16 + lr;
            af[ri] = *(const short8*)
                &Bs[R * 32 + ((lq ^ ((R >> 1) & 3))) * 8];
        }
        #pragma unroll
        for (int rj = 0; rj < 4; ++rj) {
            int R = wj * 64 + rj * 16 + lr;
            bv[rj] = *(const short8*)
                &As[R * 32 + ((lq ^ ((R >> 1) & 3))) * 8];
        }
        __builtin_amdgcn_s_setprio(1);
        #pragma unroll
        for (int ri = 0; ri < 4; ++ri)
            #pragma unroll
            for (int rj = 0; rj < 4; ++rj)
                acc[ri][rj] = __builtin_amdgcn_mfma_f32_16x16x32_bf16(
                    af[ri], bv[rj], acc[ri][rj], 0, 0, 0);
        __builtin_amdgcn_s_setprio(0);

        if (it < 13) {
            WAIT_VM_BARRIER(4);   // stage(it+1) done; it+2,it+3 in flight
        } else if (it == 13) {
            WAIT_VM_BARRIER(2);   // stage14 done; stage15 in flight
        } else if (it == 14) {
            WAIT_VM_BARRIER(0);
        }
    }

    // branchless epilogue: C/D layout col = lane&15, row = quad*4 + reg
    int   ljv[4]; float najv[4];
    #pragma unroll
    for (int rj = 0; rj < 4; ++rj) {
        int jl = wj * 64 + rj * 16 + lr;
        ljv[rj]  = labels[tj + jl];
        najv[rj] = na[tj + jl];
    }
    #pragma unroll
    for (int ri = 0; ri < 4; ++ri) {
        float rs[4] = {0.f, 0.f, 0.f, 0.f};
        int liv[4]; float nbv[4];
        #pragma unroll
        for (int r = 0; r < 4; ++r) {
            int il = wi * 64 + ri * 16 + lq * 4 + r;
            liv[r] = labels[ti + il];
            nbv[r] = nb[ti + il];
        }
        #pragma unroll
        for (int rj = 0; rj < 4; ++rj)
            #pragma unroll
            for (int r = 0; r < 4; ++r) {
                float dsq  = nbv[r] + najv[rj] - 2.f * acc[ri][rj][r];
                float D    = fast_sqrt_pos(dsq);
                float mask = (liv[r] != ljv[rj]) ? 1.f : 0.f;
                rs[r] = fmaf(mask, __expf(MARGIN - D), rs[r]);
            }
        #pragma unroll
        for (int r = 0; r < 4; ++r) {
            #pragma unroll
            for (int o = 8; o > 0; o >>= 1) rs[r] += __shfl_down(rs[r], o, 16);
        }
        if (lr == 0) {
            #pragma unroll
            for (int r = 0; r < 4; ++r)
                rpart[wj][wi * 64 + ri * 16 + lq * 4 + r] = rs[r];
        }
    }
    __syncthreads();
    if (t < 256) {
        float s = rpart[0][t] + rpart[1][t] + rpart[2][t] + rpart[3][t];
        atomicAdd(&rns[ti + t], s);
    }
}

// ---------------------------------------------------------------------------
// Phase-2 (champion config: 256 blocks — r9's measured-best): same-label
// 64x64 tiles, gathered-row GEMM, 512 threads (8 waves 2x4), SINGLE-SLAB
// whole 64x512 A/B tiles in 128KB LDS (16 glds16/thread), ONE vmcnt(0)
// drain, 16 K-slices barrier-free. Last block writes final output.
// ---------------------------------------------------------------------------
__global__ __launch_bounds__(512) void pass2_pos(
    const unsigned short* __restrict__ abf, const unsigned short* __restrict__ bbf,
    const float* __restrict__ na, const float* __restrict__ nb,
    const float* __restrict__ rns,
    const int* __restrict__ perm, const int* __restrict__ goff,
    const int* __restrict__ wl, const int* __restrict__ wlmeta,
    float* __restrict__ loss_sum, int* __restrict__ done,
    float* __restrict__ out)
{
    __shared__ __align__(16) unsigned short arena[65536];  // As 64KB | Bs 64KB
    __shared__ int   rows_i[64], rows_j[64];
    __shared__ float rbi_s[64], rbj_s[64], nbi_s[64], naj_s[64];
    __shared__ float part[8];

    const int t    = threadIdx.x;
    const int lane = t & 63;
    const int w    = t >> 6;          // 0..7
    const int wi   = w >> 2;          // 0..1  (i-half, 32 rows)
    const int wj   = w & 3;           // 0..3  (j-quarter, 16 cols)
    const int lr   = lane & 15;
    const int lq   = lane >> 4;
    const int nwl  = wlmeta[0];

    float local = 0.f;

    for (int item = blockIdx.x; item < nwl; item += gridDim.x) {
        __syncthreads();   // previous item's readers done with meta/arena
        int e  = wl[item];
        int g  = e >> 12, ti = (e >> 6) & 63, tj = e & 63;
        int gb = goff[g], ge = goff[g + 1];
        int cnt = ge - gb;

        if (t < 64) {
            int idx = gb + ti * 64 + t;
            int ig  = perm[idx < ge ? idx : gb];   // pad with first row of group
            rows_i[t] = ig;
            rbi_s[t]  = rns[ig];
            nbi_s[t]  = nb[ig];
        } else if (t < 128) {
            int u   = t - 64;
            int idx = gb + tj * 64 + u;
            int jg  = perm[idx < ge ? idx : gb];
            rows_j[u] = jg;
            rbj_s[u]  = rns[jg];
            naj_s[u]  = na[jg];
        }
        __syncthreads();

        // stage entire 64x512 tiles: per side 4096 chunks (row=c>>6, q=c&63),
        // 8 c-rounds x 2 sides = 16 glds16/thread; source pre-swizzled
        // q^(row&7) (stays within 128B group so coalescing unchanged).
        #pragma unroll
        for (int l = 0; l < 8; ++l) {
            int c   = t + l * 512;           // 0..4095
            int row = c >> 6;
            int qs  = (c & 63) ^ (row & 7);
            glds16(abf + (size_t)rows_j[row] * FDIM + qs * 8, arena + c * 8);
            glds16(bbf + (size_t)rows_i[row] * FDIM + qs * 8,
                   arena + 32768 + c * 8);
        }
        WAIT_VM_BARRIER(0);

        floatx4 acc[2];
        acc[0] = (floatx4){0.f, 0.f, 0.f, 0.f};
        acc[1] = (floatx4){0.f, 0.f, 0.f, 0.f};

        const unsigned short* As = arena;           // a-side (cols j)
        const unsigned short* Bs = arena + 32768;   // b-side (rows i)
        #pragma unroll
        for (int ks = 0; ks < 16; ++ks) {
            short8 af[2], bv;
            #pragma unroll
            for (int ri = 0; ri < 2; ++ri) {
                int R  = wi * 32 + ri * 16 + lr;
                int cs = (ks * 4 + lq) ^ (R & 7);
                af[ri] = *(const short8*)&Bs[R * 512 + cs * 8];
            }
            {
                int R  = wj * 16 + lr;
                int cs = (ks * 4 + lq) ^ (R & 7);
                bv = *(const short8*)&As[R * 512 + cs * 8];
            }
            #pragma unroll
            for (int ri = 0; ri < 2; ++ri)
                acc[ri] = __builtin_amdgcn_mfma_f32_16x16x32_bf16(
                    af[ri], bv, acc[ri], 0, 0, 0);
        }

        // epilogue: J = log(rns_i + rns_j) + D, hinged, squared
        int  jl  = wj * 16 + lr;
        bool vj  = (tj * 64 + jl) < cnt;
        int  jg  = rows_j[jl];
        float nav = naj_s[jl], rbj = rbj_s[jl];
        #pragma unroll
        for (int ri = 0; ri < 2; ++ri) {
            #pragma unroll
            for (int r = 0; r < 4; ++r) {
                int  il = wi * 32 + ri * 16 + lq * 4 + r;
                bool vi = (ti * 64 + il) < cnt;
                if (vi && vj && rows_i[il] != jg) {
                    float dsq = nbi_s[il] + nav - 2.f * acc[ri][r];
                    float D   = fast_sqrt_pos(dsq);
                    float J   = __logf(rbi_s[il] + rbj) + D;
                    float h   = fmaxf(J, 0.f);
                    local += h * h;
                }
            }
        }
    }

    #pragma unroll
    for (int o = 32; o > 0; o >>= 1) local += __shfl_down(local, o);
    if (lane == 0) part[w] = local;
    __syncthreads();
    if (t == 0) {
        float s = 0.f;
        #pragma unroll
        for (int i = 0; i < 8; ++i) s += part[i];
        atomicAdd(loss_sum, s);
        __threadfence();
        int old = atomicAdd(done, 1);
        if (old == (int)gridDim.x - 1) {
            __threadfence();
            float total = *(volatile float*)loss_sum;
            out[0] = total / (2.0f * (float)wlmeta[1]);
        }
    }
}

// ---------------------------------------------------------------------------
extern "C" void kernel_launch(void* const* d_in, const int* in_sizes, int n_in,
                              void* d_out, int out_size, void* d_ws, size_t ws_size,
                              hipStream_t stream) {
    const float* a      = (const float*)d_in[0];
    const float* b      = (const float*)d_in[1];
    const int*   labels = (const int*)d_in[2];
    float* out = (float*)d_out;

    // ws: abf(4MB) | bbf(4MB) | na,nb,rns,loss | perm,goff,wlmeta,wl  (~8.5MB)
    unsigned short* abf = (unsigned short*)d_ws;
    unsigned short* bbf = abf + (size_t)NROW * FDIM;
    float* fws  = (float*)(bbf + (size_t)NROW * FDIM);
    float* na   = fws;
    float* nb   = fws + NROW;
    float* rns  = fws + 2 * NROW;
    float* loss = fws + 3 * NROW;
    int* iws    = (int*)(fws + 3 * NROW + 4);
    int* perm   = iws;                 // NROW
    int* goff   = iws + NROW;          // 17
    int* wlmeta = iws + NROW + 20;     // [0]=n, [1]=num_pos, [2]=done
    int* wl     = iws + NROW + 24;     // <= 8192 worst case

    prep_kernel<<<PREP_BLK + 1, 256, 0, stream>>>(a, b, labels, abf, bbf,
                                                  na, nb, rns, loss,
                                                  perm, goff, wl, wlmeta);
    pass_neg<<<(NROW / 256) * (NROW / 256), 1024, 0, stream>>>(abf, bbf, labels,
                                                               na, nb, rns);
    pass2_pos<<<256, 512, 0, stream>>>(abf, bbf, na, nb, rns, perm, goff, wl,
                                       wlmeta, loss, &wlmeta[2], out);
}